// Round 2
// baseline (2798.354 us; speedup 1.0000x reference)
//
#include <hip/hip_runtime.h>

typedef __bf16 bf16_t;
typedef bf16_t bf16x8 __attribute__((ext_vector_type(8)));
typedef float f32x4 __attribute__((ext_vector_type(4)));
typedef unsigned short u16;

#define P_TOTAL 98304
#define PTS_PER_BATCH 49152

__device__ __forceinline__ u16 f2bs(float f){ bf16_t b=(bf16_t)f; return __builtin_bit_cast(u16,b); }

// ---------- weight transpose: (K,N) fp32 -> (N,K) bf16 ----------
__global__ void k_wtrans15(const float* __restrict__ lz, const float* __restrict__ f0,
                           const float* __restrict__ f1, u16* __restrict__ dst){
  __shared__ float tile[32][33];
  int z = blockIdx.z;
  const float* src = (z<5) ? (lz + (size_t)z*262144)
                   : (z<10 ? (f0 + (size_t)(z-5)*262144)
                           : (f1 + (size_t)(z-10)*262144));
  u16* d = dst + (size_t)z*262144;
  int k0 = blockIdx.x*32, n0 = blockIdx.y*32;
  int t = threadIdx.x, a = t&31, r = t>>5;
  #pragma unroll
  for (int p=0;p<4;p++) tile[r+p*8][a] = src[(size_t)(k0+r+p*8)*512 + n0+a];
  __syncthreads();
  #pragma unroll
  for (int p=0;p<4;p++) d[(size_t)(n0+r+p*8)*512 + k0+a] = f2bs(tile[a][r+p*8]);
}

__global__ void k_wtrans_in(const float* __restrict__ w, u16* __restrict__ dst){
  __shared__ float tile[32][33];
  int k0 = blockIdx.x*32, n0 = blockIdx.y*32;
  int t = threadIdx.x, a = t&31, r = t>>5;
  #pragma unroll
  for (int p=0;p<4;p++){
    int k = k0+r+p*8;
    tile[r+p*8][a] = (k < 63) ? w[(size_t)k*512 + n0+a] : 0.f;
  }
  __syncthreads();
  #pragma unroll
  for (int p=0;p<4;p++) dst[(size_t)(n0+r+p*8)*64 + k0+a] = f2bs(tile[a][r+p*8]);
}

// ---------- feature transpose: (B,512,128,128) f32 -> (B,128,128,512) bf16 ----------
__global__ void k_featT(const float* __restrict__ feat, u16* __restrict__ featT){
  int x = threadIdx.x;            // 0..127
  int c8 = blockIdx.x*8;          // channel octet
  int y = blockIdx.y, b = blockIdx.z;
  float v[8];
  #pragma unroll
  for (int j=0;j<8;j++)
    v[j] = feat[(((size_t)(b*512 + c8 + j))*128 + y)*128 + x];
  bf16x8 o;
  #pragma unroll
  for (int j=0;j<8;j++) o[j] = (bf16_t)v[j];
  *(bf16x8*)(featT + (((size_t)(b*128 + y))*128 + x)*512 + c8) = o;
}

// ---------- per-point: geometry + bilinear + positional encoding ----------
__global__ void k_points(const float* __restrict__ world, const float* __restrict__ c2w,
                         const float* __restrict__ kmat, const u16* __restrict__ featT,
                         u16* __restrict__ alignedB, u16* __restrict__ encB){
  int wid = threadIdx.x >> 6, lane = threadIdx.x & 63;
  int gp = blockIdx.x*4 + wid;
  int b = gp / PTS_PER_BATCH;
  const float* wp = world + (size_t)gp*3;
  float px = wp[0], py = wp[1], pz = wp[2];
  const float* cw = c2w + b*16;
  float dx = px - cw[3], dy = py - cw[7], dz = pz - cw[11];
  float cx = cw[0]*dx + cw[4]*dy + cw[8]*dz;
  float cy = cw[1]*dx + cw[5]*dy + cw[9]*dz;
  float cz = cw[2]*dx + cw[6]*dy + cw[10]*dz;
  const float* km = kmat + b*9;
  float u0 = km[0]*cx + km[1]*cy + km[2]*cz;
  float v0 = km[3]*cx + km[4]*cy + km[5]*cz;
  float zz = km[6]*cx + km[7]*cy + km[8]*cz;
  if (fabsf(zz) < 1e-6f) zz = 1e-6f;
  float uu = u0/zz, vv = v0/zz;
  float xf = fminf(fmaxf(uu, 0.f), 127.f);
  float yf = fminf(fmaxf(vv, 0.f), 127.f);
  float x0f = floorf(xf), y0f = floorf(yf);
  int x0 = (int)x0f, y0 = (int)y0f;
  int x1 = min(x0+1,127), y1 = min(y0+1,127);
  float wx = xf - x0f, wy = yf - y0f;
  float w00 = (1.f-wx)*(1.f-wy), w01 = wx*(1.f-wy), w10 = (1.f-wx)*wy, w11 = wx*wy;
  size_t fb = (size_t)b*128*128*512;
  int c8 = lane*8;
  const bf16x8 t00 = *(const bf16x8*)(featT + fb + (size_t)(y0*128+x0)*512 + c8);
  const bf16x8 t01 = *(const bf16x8*)(featT + fb + (size_t)(y0*128+x1)*512 + c8);
  const bf16x8 t10 = *(const bf16x8*)(featT + fb + (size_t)(y1*128+x0)*512 + c8);
  const bf16x8 t11 = *(const bf16x8*)(featT + fb + (size_t)(y1*128+x1)*512 + c8);
  bf16x8 o;
  #pragma unroll
  for (int j=0;j<8;j++){
    float r = (float)t00[j]*w00 + (float)t01[j]*w01 + (float)t10[j]*w10 + (float)t11[j]*w11;
    o[j] = (bf16_t)r;
  }
  *(bf16x8*)(alignedB + (size_t)gp*512 + c8) = o;
  float cam[3] = {cx, cy, cz};
  float e;
  if (lane < 3) e = cam[lane];
  else if (lane < 33){
    int i = (lane-3)/10, f = (lane-3)%10;
    e = sinf(6.2831855f * cam[i] * (float)(1<<f));
  } else if (lane < 63){
    int i = (lane-33)/10, f = (lane-33)%10;
    e = cosf(6.2831855f * cam[i] * (float)(1<<f));
  } else e = 0.f;
  encB[(size_t)gp*64 + lane] = f2bs(e);
}

// ============ fused persistent MLP ============
// block = 512 thr (8 waves), each block owns 32 points.
// wave w owns n-strip [w*64, w*64+64); h residual fp32 in registers (C-layout),
// activations cross waves via one 32KB swizzled bf16 LDS buffer.
// B-fragments (weights, (N,K) bf16) read directly from global (L2-resident).

// K-loop over NK chunks of BK=32, A from swizzled LDS, accumulate into acc
template<int NK>
__device__ __forceinline__ void gemm_acc(const u16* sA, const u16* __restrict__ Bt, int ldb,
                                         int wn, int fm, int fk8, f32x4 (&acc)[2][4]){
  #pragma unroll 2
  for (int kt=0; kt<NK; ++kt){
    const int k0 = kt*32;
    bf16x8 b[4], a[2];
    #pragma unroll
    for (int nt=0;nt<4;nt++)
      b[nt] = *(const bf16x8*)(Bt + (size_t)(wn + nt*16 + fm)*ldb + k0 + fk8*8);
    #pragma unroll
    for (int mt=0;mt<2;mt++){
      int m = mt*16 + fm;
      int kc = kt*4 + fk8;
      a[mt] = *(const bf16x8*)&sA[m*512 + ((kc ^ (m&7))<<3)];
    }
    #pragma unroll
    for (int mt=0;mt<2;mt++)
      #pragma unroll
      for (int nt=0;nt<4;nt++)
        acc[mt][nt] = __builtin_amdgcn_mfma_f32_16x16x32_bf16(a[mt], b[nt], acc[mt][nt], 0,0,0);
  }
}

__device__ __forceinline__ void add_bias(const float* __restrict__ bias, int wn, int fm,
                                         f32x4 (&acc)[2][4]){
  #pragma unroll
  for (int nt=0;nt<4;nt++){
    float bv = bias[wn + nt*16 + fm];
    #pragma unroll
    for (int mt=0;mt<2;mt++)
      #pragma unroll
      for (int r=0;r<4;r++) acc[mt][nt][r] += bv;
  }
}

// write relu(acc) as bf16 into swizzled LDS act buffer (C-layout: col=l&15, row=(l>>4)*4+r)
__device__ __forceinline__ void write_relu(u16* dst, int l, int wn, f32x4 (&acc)[2][4]){
  const int fm = l&15, rq = (l>>4)*4;
  #pragma unroll
  for (int mt=0;mt<2;mt++)
    #pragma unroll
    for (int nt=0;nt<4;nt++){
      int k = wn + nt*16 + fm;
      #pragma unroll
      for (int r=0;r<4;r++){
        int m = mt*16 + rq + r;
        dst[m*512 + ((((k>>3) ^ (m&7))<<3) | (k&7))] = f2bs(fmaxf(acc[mt][nt][r], 0.f));
      }
    }
}

__global__ __launch_bounds__(512, 4) void k_net(
    const u16* __restrict__ alignedB, const u16* __restrict__ encB,
    const u16* __restrict__ wtin, const float* __restrict__ b_in,
    const u16* __restrict__ wts, const float* __restrict__ bz,
    const float* __restrict__ b0, const float* __restrict__ b1,
    const float* __restrict__ wout, const float* __restrict__ bout,
    float* __restrict__ out)
{
  __shared__ u16 albuf[32*512];   // aligned features, swizzled, persistent
  __shared__ u16 actbuf[32*512];  // current activation (A operand), swizzled
  const int t = threadIdx.x, w = t>>6, l = t&63;
  const int m0 = blockIdx.x*32;
  const int wn = w*64, fm = l&15, fk8 = l>>4;

  // copy aligned[m0:m0+32][0:512] -> albuf (512 thr x 64B)
  {
    int m = t>>4, c4 = t&15;
    const uint4* src = (const uint4*)(alignedB + (size_t)(m0+m)*512 + c4*32);
    #pragma unroll
    for (int j=0;j<4;j++){
      int kc = c4*4 + j;
      *(uint4*)&albuf[m*512 + ((kc ^ (m&7))<<3)] = src[j];
    }
  }
  // copy enc[m0:m0+32][0:64] -> actbuf (first 256 thr)
  if (t < 256){
    int m = t>>3, kc = t&7;
    *(uint4*)&actbuf[m*512 + ((kc ^ (m&7))<<3)] =
        *(const uint4*)(encB + (size_t)(m0+m)*64 + kc*8);
  }
  __syncthreads();

  f32x4 h[2][4] = {};
  gemm_acc<2>(actbuf, wtin, 64, wn, fm, fk8, h);
  add_bias(b_in, wn, fm, h);

  for (int i=0;i<5;i++){
    // h += aligned @ Wz + bz   (A from albuf: no actbuf dependency)
    gemm_acc<16>(albuf, wts + (size_t)i*262144, 512, wn, fm, fk8, h);
    add_bias(bz + i*512, wn, fm, h);
    __syncthreads();                       // all waves done reading actbuf
    write_relu(actbuf, l, wn, h);          // actbuf = relu(h)
    __syncthreads();
    f32x4 acc[2][4] = {};
    gemm_acc<16>(actbuf, wts + (size_t)(5+i)*262144, 512, wn, fm, fk8, acc);
    add_bias(b0 + i*512, wn, fm, acc);
    __syncthreads();
    write_relu(actbuf, l, wn, acc);        // actbuf = relu(net)
    __syncthreads();
    // h += act @ W1 + b1
    gemm_acc<16>(actbuf, wts + (size_t)(10+i)*262144, 512, wn, fm, fk8, h);
    add_bias(b1 + i*512, wn, fm, h);
  }

  // sigma = exp(relu(h) . wout + bout), reduce n across lanes then waves
  float s[2][4];
  #pragma unroll
  for (int mt=0;mt<2;mt++)
    #pragma unroll
    for (int r=0;r<4;r++){
      float a = 0.f;
      #pragma unroll
      for (int nt=0;nt<4;nt++)
        a += fmaxf(h[mt][nt][r], 0.f) * wout[wn + nt*16 + fm];
      s[mt][r] = a;
    }
  #pragma unroll
  for (int off=1; off<16; off<<=1)
    #pragma unroll
    for (int mt=0;mt<2;mt++)
      #pragma unroll
      for (int r=0;r<4;r++)
        s[mt][r] += __shfl_xor(s[mt][r], off, 64);
  __syncthreads();                 // actbuf dead; reuse as float red[8][32]
  float* red = (float*)actbuf;
  if (fm == 0){
    int rq = (l>>4)*4;
    #pragma unroll
    for (int mt=0;mt<2;mt++)
      #pragma unroll
      for (int r=0;r<4;r++)
        red[w*32 + mt*16 + rq + r] = s[mt][r];
  }
  __syncthreads();
  if (t < 32){
    float a = bout[0];
    #pragma unroll
    for (int wv=0; wv<8; wv++) a += red[wv*32 + t];
    out[m0 + t] = expf(a);
  }
}

extern "C" void kernel_launch(void* const* d_in, const int* in_sizes, int n_in,
                              void* d_out, int out_size, void* d_ws, size_t ws_size,
                              hipStream_t stream) {
  const float* world = (const float*)d_in[0];
  const float* c2w   = (const float*)d_in[1];
  const float* kmat  = (const float*)d_in[2];
  const float* feat  = (const float*)d_in[3];
  const float* w_in  = (const float*)d_in[4];
  const float* b_in  = (const float*)d_in[5];
  const float* w_z   = (const float*)d_in[6];
  const float* b_z   = (const float*)d_in[7];
  const float* w_f0  = (const float*)d_in[8];
  const float* b_f0  = (const float*)d_in[9];
  const float* w_f1  = (const float*)d_in[10];
  const float* b_f1  = (const float*)d_in[11];
  const float* w_out = (const float*)d_in[12];
  const float* b_out = (const float*)d_in[13];
  float* out = (float*)d_out;
  char* ws = (char*)d_ws;

  size_t off = 0;
  u16* wts   = (u16*)(ws + off); off += (size_t)15*262144*2;       // 15x (512n x 512k) bf16
  u16* wtin  = (u16*)(ws + off); off += (size_t)512*64*2;          // (512n x 64k) bf16
  u16* featT = (u16*)(ws + off); off += (size_t)2*128*128*512*2;   // transposed features
  u16* alignedB = (u16*)(ws + off); off += (size_t)P_TOTAL*512*2;  // sampled features bf16
  u16* encB  = (u16*)(ws + off); off += (size_t)P_TOTAL*64*2;      // positional enc bf16

  k_wtrans15<<<dim3(16,16,15), 256, 0, stream>>>(w_z, w_f0, w_f1, wts);
  k_wtrans_in<<<dim3(2,16,1), 256, 0, stream>>>(w_in, wtin);
  k_featT<<<dim3(64,128,2), 128, 0, stream>>>(feat, featT);
  k_points<<<dim3(P_TOTAL/4), 256, 0, stream>>>(world, c2w, kmat, featT, alignedB, encB);
  k_net<<<dim3(P_TOTAL/32), 512, 0, stream>>>(alignedB, encB, wtin, b_in, wts,
      b_z, b_f0, b_f1, w_out, b_out, out);
}

// Round 3
// 2643.153 us; speedup vs baseline: 1.0587x; 1.0587x over previous
//
#include <hip/hip_runtime.h>

typedef __bf16 bf16_t;
typedef bf16_t bf16x8 __attribute__((ext_vector_type(8)));
typedef float f32x4 __attribute__((ext_vector_type(4)));
typedef unsigned short u16;

#define P_TOTAL 98304
#define PTS_PER_BATCH 49152

__device__ __forceinline__ u16 f2bs(float f){ bf16_t b=(bf16_t)f; return __builtin_bit_cast(u16,b); }

// ---------- weight transpose: (K,N) fp32 -> (N,K) bf16 ----------
__global__ void k_wtrans15(const float* __restrict__ lz, const float* __restrict__ f0,
                           const float* __restrict__ f1, u16* __restrict__ dst){
  __shared__ float tile[32][33];
  int z = blockIdx.z;
  const float* src = (z<5) ? (lz + (size_t)z*262144)
                   : (z<10 ? (f0 + (size_t)(z-5)*262144)
                           : (f1 + (size_t)(z-10)*262144));
  u16* d = dst + (size_t)z*262144;
  int k0 = blockIdx.x*32, n0 = blockIdx.y*32;
  int t = threadIdx.x, a = t&31, r = t>>5;
  #pragma unroll
  for (int p=0;p<4;p++) tile[r+p*8][a] = src[(size_t)(k0+r+p*8)*512 + n0+a];
  __syncthreads();
  #pragma unroll
  for (int p=0;p<4;p++) d[(size_t)(n0+r+p*8)*512 + k0+a] = f2bs(tile[a][r+p*8]);
}

__global__ void k_wtrans_in(const float* __restrict__ w, u16* __restrict__ dst){
  __shared__ float tile[32][33];
  int k0 = blockIdx.x*32, n0 = blockIdx.y*32;
  int t = threadIdx.x, a = t&31, r = t>>5;
  #pragma unroll
  for (int p=0;p<4;p++){
    int k = k0+r+p*8;
    tile[r+p*8][a] = (k < 63) ? w[(size_t)k*512 + n0+a] : 0.f;
  }
  __syncthreads();
  #pragma unroll
  for (int p=0;p<4;p++) dst[(size_t)(n0+r+p*8)*64 + k0+a] = f2bs(tile[a][r+p*8]);
}

// ---------- feature transpose: (B,512,128,128) f32 -> (B,128,128,512) bf16 ----------
__global__ void k_featT(const float* __restrict__ feat, u16* __restrict__ featT){
  int x = threadIdx.x;
  int c8 = blockIdx.x*8;
  int y = blockIdx.y, b = blockIdx.z;
  float v[8];
  #pragma unroll
  for (int j=0;j<8;j++)
    v[j] = feat[(((size_t)(b*512 + c8 + j))*128 + y)*128 + x];
  bf16x8 o;
  #pragma unroll
  for (int j=0;j<8;j++) o[j] = (bf16_t)v[j];
  *(bf16x8*)(featT + (((size_t)(b*128 + y))*128 + x)*512 + c8) = o;
}

// ---------- per-point: geometry + bilinear + positional encoding ----------
__global__ void k_points(const float* __restrict__ world, const float* __restrict__ c2w,
                         const float* __restrict__ kmat, const u16* __restrict__ featT,
                         u16* __restrict__ alignedB, u16* __restrict__ encB){
  int wid = threadIdx.x >> 6, lane = threadIdx.x & 63;
  int gp = blockIdx.x*4 + wid;
  int b = gp / PTS_PER_BATCH;
  const float* wp = world + (size_t)gp*3;
  float px = wp[0], py = wp[1], pz = wp[2];
  const float* cw = c2w + b*16;
  float dx = px - cw[3], dy = py - cw[7], dz = pz - cw[11];
  float cx = cw[0]*dx + cw[4]*dy + cw[8]*dz;
  float cy = cw[1]*dx + cw[5]*dy + cw[9]*dz;
  float cz = cw[2]*dx + cw[6]*dy + cw[10]*dz;
  const float* km = kmat + b*9;
  float u0 = km[0]*cx + km[1]*cy + km[2]*cz;
  float v0 = km[3]*cx + km[4]*cy + km[5]*cz;
  float zz = km[6]*cx + km[7]*cy + km[8]*cz;
  if (fabsf(zz) < 1e-6f) zz = 1e-6f;
  float uu = u0/zz, vv = v0/zz;
  float xf = fminf(fmaxf(uu, 0.f), 127.f);
  float yf = fminf(fmaxf(vv, 0.f), 127.f);
  float x0f = floorf(xf), y0f = floorf(yf);
  int x0 = (int)x0f, y0 = (int)y0f;
  int x1 = min(x0+1,127), y1 = min(y0+1,127);
  float wx = xf - x0f, wy = yf - y0f;
  float w00 = (1.f-wx)*(1.f-wy), w01 = wx*(1.f-wy), w10 = (1.f-wx)*wy, w11 = wx*wy;
  size_t fb = (size_t)b*128*128*512;
  int c8 = lane*8;
  const bf16x8 t00 = *(const bf16x8*)(featT + fb + (size_t)(y0*128+x0)*512 + c8);
  const bf16x8 t01 = *(const bf16x8*)(featT + fb + (size_t)(y0*128+x1)*512 + c8);
  const bf16x8 t10 = *(const bf16x8*)(featT + fb + (size_t)(y1*128+x0)*512 + c8);
  const bf16x8 t11 = *(const bf16x8*)(featT + fb + (size_t)(y1*128+x1)*512 + c8);
  bf16x8 o;
  #pragma unroll
  for (int j=0;j<8;j++){
    float r = (float)t00[j]*w00 + (float)t01[j]*w01 + (float)t10[j]*w10 + (float)t11[j]*w11;
    o[j] = (bf16_t)r;
  }
  *(bf16x8*)(alignedB + (size_t)gp*512 + c8) = o;
  float cam[3] = {cx, cy, cz};
  float e;
  if (lane < 3) e = cam[lane];
  else if (lane < 33){
    int i = (lane-3)/10, f = (lane-3)%10;
    e = sinf(6.2831855f * cam[i] * (float)(1<<f));
  } else if (lane < 63){
    int i = (lane-33)/10, f = (lane-33)%10;
    e = cosf(6.2831855f * cam[i] * (float)(1<<f));
  } else e = 0.f;
  encB[(size_t)gp*64 + lane] = f2bs(e);
}

// ============ fused persistent MLP (M=64/block) ============
// 512 thr (8 waves); wave w owns n-strip [w*64, w*64+64); each wave does all 4 m-tiles.
// h residual fp32 in regs (64 VGPR, C-layout). Single 64KB swizzled LDS activation
// buffer; aligned re-staged into it per layer. Weights (N,K) bf16 streamed from
// global (L2-broadcast) with 1-chunk register double-buffer.

template<int NK>
__device__ __forceinline__ void gemm_lds(const u16* sA, const u16* __restrict__ Bt, int ldb,
                                         int wn, int fm, int fk8, f32x4 (&acc)[4][4]){
  bf16x8 b[4];
  #pragma unroll
  for (int nt=0;nt<4;nt++)
    b[nt] = *(const bf16x8*)(Bt + (size_t)(wn + nt*16 + fm)*ldb + fk8*8);
  #pragma unroll
  for (int kt=0; kt<NK; ++kt){
    bf16x8 bn[4];
    if (kt+1 < NK){
      const int k0 = (kt+1)*32;
      #pragma unroll
      for (int nt=0;nt<4;nt++)
        bn[nt] = *(const bf16x8*)(Bt + (size_t)(wn + nt*16 + fm)*ldb + k0 + fk8*8);
    }
    bf16x8 a[4];
    #pragma unroll
    for (int mt=0;mt<4;mt++){
      int m = mt*16 + fm;
      int kc = kt*4 + fk8;
      a[mt] = *(const bf16x8*)&sA[m*512 + ((kc ^ (m&7))<<3)];
    }
    #pragma unroll
    for (int mt=0;mt<4;mt++)
      #pragma unroll
      for (int nt=0;nt<4;nt++)
        acc[mt][nt] = __builtin_amdgcn_mfma_f32_16x16x32_bf16(a[mt], b[nt], acc[mt][nt], 0,0,0);
    if (kt+1 < NK){
      #pragma unroll
      for (int nt=0;nt<4;nt++) b[nt] = bn[nt];
    }
  }
}

__device__ __forceinline__ void add_bias(const float* __restrict__ bias, int wn, int fm,
                                         f32x4 (&acc)[4][4]){
  #pragma unroll
  for (int nt=0;nt<4;nt++){
    float bv = bias[wn + nt*16 + fm];
    #pragma unroll
    for (int mt=0;mt<4;mt++)
      #pragma unroll
      for (int r=0;r<4;r++) acc[mt][nt][r] += bv;
  }
}

__device__ __forceinline__ void write_relu(u16* dst, int l, int wn, f32x4 (&acc)[4][4]){
  const int fm = l&15, rq = (l>>4)*4;
  #pragma unroll
  for (int mt=0;mt<4;mt++)
    #pragma unroll
    for (int nt=0;nt<4;nt++){
      int k = wn + nt*16 + fm;
      #pragma unroll
      for (int r=0;r<4;r++){
        int m = mt*16 + rq + r;
        dst[m*512 + ((((k>>3) ^ (m&7))<<3) | (k&7))] = f2bs(fmaxf(acc[mt][nt][r], 0.f));
      }
    }
}

// stage 64x512 bf16 row-major global tile -> swizzled LDS
__device__ __forceinline__ void stage_tile(u16* dst, const u16* __restrict__ src, int t){
  int m = t>>3, g = t&7;
  #pragma unroll
  for (int j=0;j<8;j++){
    int kc = g*8 + j;
    *(uint4*)&dst[m*512 + ((kc ^ (m&7))<<3)] =
        *(const uint4*)(src + (size_t)m*512 + kc*8);
  }
}

__global__ __launch_bounds__(512, 4) void k_net(
    const u16* __restrict__ alignedB, const u16* __restrict__ encB,
    const u16* __restrict__ wtin, const float* __restrict__ b_in,
    const u16* __restrict__ wts, const float* __restrict__ bz,
    const float* __restrict__ b0, const float* __restrict__ b1,
    const float* __restrict__ wout, const float* __restrict__ bout,
    float* __restrict__ out)
{
  __shared__ u16 actbuf[64*512];   // 64 KB
  const int t = threadIdx.x, w = t>>6, l = t&63;
  const int m0 = blockIdx.x*64;
  const int wn = w*64, fm = l&15, fk8 = l>>4;

  // stage enc[m0:m0+64][0:64] (first 256 threads)
  if (t < 256){
    int m = t>>2;
    #pragma unroll
    for (int j=0;j<2;j++){
      int kc = (t&3)*2 + j;
      *(uint4*)&actbuf[m*512 + ((kc ^ (m&7))<<3)] =
          *(const uint4*)(encB + (size_t)(m0+m)*64 + kc*8);
    }
  }
  __syncthreads();

  f32x4 h[4][4] = {};
  gemm_lds<2>(actbuf, wtin, 64, wn, fm, fk8, h);
  add_bias(b_in, wn, fm, h);

  for (int i=0;i<5;i++){
    __syncthreads();                                   // readers of actbuf done
    stage_tile(actbuf, alignedB + (size_t)m0*512, t);  // actbuf = aligned tile
    __syncthreads();
    gemm_lds<16>(actbuf, wts + (size_t)i*262144, 512, wn, fm, fk8, h);
    add_bias(bz + i*512, wn, fm, h);
    __syncthreads();
    write_relu(actbuf, l, wn, h);                      // actbuf = relu(h)
    __syncthreads();
    f32x4 acc[4][4] = {};
    gemm_lds<16>(actbuf, wts + (size_t)(5+i)*262144, 512, wn, fm, fk8, acc);
    add_bias(b0 + i*512, wn, fm, acc);
    __syncthreads();
    write_relu(actbuf, l, wn, acc);                    // actbuf = relu(net)
    __syncthreads();
    gemm_lds<16>(actbuf, wts + (size_t)(10+i)*262144, 512, wn, fm, fk8, h);
    add_bias(b1 + i*512, wn, fm, h);
  }

  // sigma = exp(relu(h) . wout + bout)
  float s[4][4];
  #pragma unroll
  for (int mt=0;mt<4;mt++)
    #pragma unroll
    for (int r=0;r<4;r++){
      float a = 0.f;
      #pragma unroll
      for (int nt=0;nt<4;nt++)
        a += fmaxf(h[mt][nt][r], 0.f) * wout[wn + nt*16 + fm];
      s[mt][r] = a;
    }
  #pragma unroll
  for (int off=1; off<16; off<<=1)
    #pragma unroll
    for (int mt=0;mt<4;mt++)
      #pragma unroll
      for (int r=0;r<4;r++)
        s[mt][r] += __shfl_xor(s[mt][r], off, 64);
  __syncthreads();                 // actbuf dead; reuse as float red[8][64]
  float* red = (float*)actbuf;
  if (fm == 0){
    int rq = (l>>4)*4;
    #pragma unroll
    for (int mt=0;mt<4;mt++)
      #pragma unroll
      for (int r=0;r<4;r++)
        red[w*64 + mt*16 + rq + r] = s[mt][r];
  }
  __syncthreads();
  if (t < 64){
    float a = bout[0];
    #pragma unroll
    for (int wv=0; wv<8; wv++) a += red[wv*64 + t];
    out[m0 + t] = expf(a);
  }
}

extern "C" void kernel_launch(void* const* d_in, const int* in_sizes, int n_in,
                              void* d_out, int out_size, void* d_ws, size_t ws_size,
                              hipStream_t stream) {
  const float* world = (const float*)d_in[0];
  const float* c2w   = (const float*)d_in[1];
  const float* kmat  = (const float*)d_in[2];
  const float* feat  = (const float*)d_in[3];
  const float* w_in  = (const float*)d_in[4];
  const float* b_in  = (const float*)d_in[5];
  const float* w_z   = (const float*)d_in[6];
  const float* b_z   = (const float*)d_in[7];
  const float* w_f0  = (const float*)d_in[8];
  const float* b_f0  = (const float*)d_in[9];
  const float* w_f1  = (const float*)d_in[10];
  const float* b_f1  = (const float*)d_in[11];
  const float* w_out = (const float*)d_in[12];
  const float* b_out = (const float*)d_in[13];
  float* out = (float*)d_out;
  char* ws = (char*)d_ws;

  size_t off = 0;
  u16* wts   = (u16*)(ws + off); off += (size_t)15*262144*2;       // 15x (512n x 512k) bf16
  u16* wtin  = (u16*)(ws + off); off += (size_t)512*64*2;          // (512n x 64k) bf16
  u16* featT = (u16*)(ws + off); off += (size_t)2*128*128*512*2;   // transposed features
  u16* alignedB = (u16*)(ws + off); off += (size_t)P_TOTAL*512*2;  // sampled features bf16
  u16* encB  = (u16*)(ws + off); off += (size_t)P_TOTAL*64*2;      // positional enc bf16

  k_wtrans15<<<dim3(16,16,15), 256, 0, stream>>>(w_z, w_f0, w_f1, wts);
  k_wtrans_in<<<dim3(2,16,1), 256, 0, stream>>>(w_in, wtin);
  k_featT<<<dim3(64,128,2), 128, 0, stream>>>(feat, featT);
  k_points<<<dim3(P_TOTAL/4), 256, 0, stream>>>(world, c2w, kmat, featT, alignedB, encB);
  k_net<<<dim3(P_TOTAL/64), 512, 0, stream>>>(alignedB, encB, wtin, b_in, wts,
      b_z, b_f0, b_f1, w_out, b_out, out);
}

// Round 4
// 1731.812 us; speedup vs baseline: 1.6159x; 1.5262x over previous
//
#include <hip/hip_runtime.h>

typedef __bf16 bf16_t;
typedef bf16_t bf16x8 __attribute__((ext_vector_type(8)));
typedef float f32x4 __attribute__((ext_vector_type(4)));
typedef unsigned short u16;

#define P_TOTAL 98304
#define PTS_PER_BATCH 49152

__device__ __forceinline__ u16 f2bs(float f){ bf16_t b=(bf16_t)f; return __builtin_bit_cast(u16,b); }

// ---------- weight transpose: (K,N) fp32 -> (N,K) bf16 ----------
__global__ void k_wtrans15(const float* __restrict__ lz, const float* __restrict__ f0,
                           const float* __restrict__ f1, u16* __restrict__ dst){
  __shared__ float tile[32][33];
  int z = blockIdx.z;
  const float* src = (z<5) ? (lz + (size_t)z*262144)
                   : (z<10 ? (f0 + (size_t)(z-5)*262144)
                           : (f1 + (size_t)(z-10)*262144));
  u16* d = dst + (size_t)z*262144;
  int k0 = blockIdx.x*32, n0 = blockIdx.y*32;
  int t = threadIdx.x, a = t&31, r = t>>5;
  #pragma unroll
  for (int p=0;p<4;p++) tile[r+p*8][a] = src[(size_t)(k0+r+p*8)*512 + n0+a];
  __syncthreads();
  #pragma unroll
  for (int p=0;p<4;p++) d[(size_t)(n0+r+p*8)*512 + k0+a] = f2bs(tile[a][r+p*8]);
}

__global__ void k_wtrans_in(const float* __restrict__ w, u16* __restrict__ dst){
  __shared__ float tile[32][33];
  int k0 = blockIdx.x*32, n0 = blockIdx.y*32;
  int t = threadIdx.x, a = t&31, r = t>>5;
  #pragma unroll
  for (int p=0;p<4;p++){
    int k = k0+r+p*8;
    tile[r+p*8][a] = (k < 63) ? w[(size_t)k*512 + n0+a] : 0.f;
  }
  __syncthreads();
  #pragma unroll
  for (int p=0;p<4;p++) dst[(size_t)(n0+r+p*8)*64 + k0+a] = f2bs(tile[a][r+p*8]);
}

// ---------- feature transpose: (B,512,128,128) f32 -> (B,128,128,512) bf16 ----------
__global__ void k_featT(const float* __restrict__ feat, u16* __restrict__ featT){
  int x = threadIdx.x;
  int c8 = blockIdx.x*8;
  int y = blockIdx.y, b = blockIdx.z;
  float v[8];
  #pragma unroll
  for (int j=0;j<8;j++)
    v[j] = feat[(((size_t)(b*512 + c8 + j))*128 + y)*128 + x];
  bf16x8 o;
  #pragma unroll
  for (int j=0;j<8;j++) o[j] = (bf16_t)v[j];
  *(bf16x8*)(featT + (((size_t)(b*128 + y))*128 + x)*512 + c8) = o;
}

// ---------- per-point: geometry + bilinear + positional encoding ----------
__global__ void k_points(const float* __restrict__ world, const float* __restrict__ c2w,
                         const float* __restrict__ kmat, const u16* __restrict__ featT,
                         u16* __restrict__ alignedB, u16* __restrict__ encB){
  int wid = threadIdx.x >> 6, lane = threadIdx.x & 63;
  int gp = blockIdx.x*4 + wid;
  int b = gp / PTS_PER_BATCH;
  const float* wp = world + (size_t)gp*3;
  float px = wp[0], py = wp[1], pz = wp[2];
  const float* cw = c2w + b*16;
  float dx = px - cw[3], dy = py - cw[7], dz = pz - cw[11];
  float cx = cw[0]*dx + cw[4]*dy + cw[8]*dz;
  float cy = cw[1]*dx + cw[5]*dy + cw[9]*dz;
  float cz = cw[2]*dx + cw[6]*dy + cw[10]*dz;
  const float* km = kmat + b*9;
  float u0 = km[0]*cx + km[1]*cy + km[2]*cz;
  float v0 = km[3]*cx + km[4]*cy + km[5]*cz;
  float zz = km[6]*cx + km[7]*cy + km[8]*cz;
  if (fabsf(zz) < 1e-6f) zz = 1e-6f;
  float uu = u0/zz, vv = v0/zz;
  float xf = fminf(fmaxf(uu, 0.f), 127.f);
  float yf = fminf(fmaxf(vv, 0.f), 127.f);
  float x0f = floorf(xf), y0f = floorf(yf);
  int x0 = (int)x0f, y0 = (int)y0f;
  int x1 = min(x0+1,127), y1 = min(y0+1,127);
  float wx = xf - x0f, wy = yf - y0f;
  float w00 = (1.f-wx)*(1.f-wy), w01 = wx*(1.f-wy), w10 = (1.f-wx)*wy, w11 = wx*wy;
  size_t fb = (size_t)b*128*128*512;
  int c8 = lane*8;
  const bf16x8 t00 = *(const bf16x8*)(featT + fb + (size_t)(y0*128+x0)*512 + c8);
  const bf16x8 t01 = *(const bf16x8*)(featT + fb + (size_t)(y0*128+x1)*512 + c8);
  const bf16x8 t10 = *(const bf16x8*)(featT + fb + (size_t)(y1*128+x0)*512 + c8);
  const bf16x8 t11 = *(const bf16x8*)(featT + fb + (size_t)(y1*128+x1)*512 + c8);
  bf16x8 o;
  #pragma unroll
  for (int j=0;j<8;j++){
    float r = (float)t00[j]*w00 + (float)t01[j]*w01 + (float)t10[j]*w10 + (float)t11[j]*w11;
    o[j] = (bf16_t)r;
  }
  *(bf16x8*)(alignedB + (size_t)gp*512 + c8) = o;
  float cam[3] = {cx, cy, cz};
  float e;
  if (lane < 3) e = cam[lane];
  else if (lane < 33){
    int i = (lane-3)/10, f = (lane-3)%10;
    e = sinf(6.2831855f * cam[i] * (float)(1<<f));
  } else if (lane < 63){
    int i = (lane-33)/10, f = (lane-33)%10;
    e = cosf(6.2831855f * cam[i] * (float)(1<<f));
  } else e = 0.f;
  encB[(size_t)gp*64 + lane] = f2bs(e);
}

// ============ fused persistent MLP (M=64/block, no spill) ============
// 512 thr (8 waves, 2/SIMD at launch_bounds(512,2) -> 256 VGPR budget).
// wave w owns n-strip [w*64,w*64+64); h fp32 resident in regs (64 VGPR, C-layout).
// albuf: aligned tile staged once (64KB); actbuf: activation tile (64KB).
// Weights (N,K) bf16 streamed from global (L2-broadcast), 1-chunk reg double-buffer.

template<int NK>
__device__ __forceinline__ void gemm_lds(const u16* sA, const u16* __restrict__ Bt, int ldb,
                                         int wn, int fm, int fk8, f32x4 (&acc)[4][4]){
  bf16x8 b[4];
  #pragma unroll
  for (int nt=0;nt<4;nt++)
    b[nt] = *(const bf16x8*)(Bt + (size_t)(wn + nt*16 + fm)*ldb + fk8*8);
  #pragma unroll
  for (int kt=0; kt<NK; ++kt){
    bf16x8 bn[4];
    if (kt+1 < NK){
      const int k0 = (kt+1)*32;
      #pragma unroll
      for (int nt=0;nt<4;nt++)
        bn[nt] = *(const bf16x8*)(Bt + (size_t)(wn + nt*16 + fm)*ldb + k0 + fk8*8);
    }
    bf16x8 a[4];
    #pragma unroll
    for (int mt=0;mt<4;mt++){
      int m = mt*16 + fm;
      int kc = kt*4 + fk8;
      a[mt] = *(const bf16x8*)&sA[m*512 + ((kc ^ (m&7))<<3)];
    }
    #pragma unroll
    for (int mt=0;mt<4;mt++)
      #pragma unroll
      for (int nt=0;nt<4;nt++)
        acc[mt][nt] = __builtin_amdgcn_mfma_f32_16x16x32_bf16(a[mt], b[nt], acc[mt][nt], 0,0,0);
    if (kt+1 < NK){
      #pragma unroll
      for (int nt=0;nt<4;nt++) b[nt] = bn[nt];
    }
  }
}

__device__ __forceinline__ void add_bias(const float* __restrict__ bias, int wn, int fm,
                                         f32x4 (&acc)[4][4]){
  #pragma unroll
  for (int nt=0;nt<4;nt++){
    float bv = bias[wn + nt*16 + fm];
    #pragma unroll
    for (int mt=0;mt<4;mt++)
      #pragma unroll
      for (int r=0;r<4;r++) acc[mt][nt][r] += bv;
  }
}

__device__ __forceinline__ void write_relu(u16* dst, int l, int wn, f32x4 (&acc)[4][4]){
  const int fm = l&15, rq = (l>>4)*4;
  #pragma unroll
  for (int mt=0;mt<4;mt++)
    #pragma unroll
    for (int nt=0;nt<4;nt++){
      int k = wn + nt*16 + fm;
      #pragma unroll
      for (int r=0;r<4;r++){
        int m = mt*16 + rq + r;
        dst[m*512 + ((((k>>3) ^ (m&7))<<3) | (k&7))] = f2bs(fmaxf(acc[mt][nt][r], 0.f));
      }
    }
}

// stage 64x512 bf16 row-major global tile -> swizzled LDS
__device__ __forceinline__ void stage_tile(u16* dst, const u16* __restrict__ src, int t){
  int m = t>>3, g = t&7;
  #pragma unroll
  for (int j=0;j<8;j++){
    int kc = g*8 + j;
    *(uint4*)&dst[m*512 + ((kc ^ (m&7))<<3)] =
        *(const uint4*)(src + (size_t)m*512 + kc*8);
  }
}

__global__ __launch_bounds__(512, 2) void k_net(
    const u16* __restrict__ alignedB, const u16* __restrict__ encB,
    const u16* __restrict__ wtin, const float* __restrict__ b_in,
    const u16* __restrict__ wts, const float* __restrict__ bz,
    const float* __restrict__ b0, const float* __restrict__ b1,
    const float* __restrict__ wout, const float* __restrict__ bout,
    float* __restrict__ out)
{
  __shared__ u16 albuf[64*512];    // aligned features, persistent (64 KB)
  __shared__ u16 actbuf[64*512];   // activation tile (64 KB)
  const int t = threadIdx.x, w = t>>6, l = t&63;
  const int m0 = blockIdx.x*64;
  const int wn = w*64, fm = l&15, fk8 = l>>4;

  // stage aligned tile once
  stage_tile(albuf, alignedB + (size_t)m0*512, t);
  // stage enc[m0:m0+64][0:64] (first 256 threads)
  if (t < 256){
    int m = t>>2;
    #pragma unroll
    for (int j=0;j<2;j++){
      int kc = (t&3)*2 + j;
      *(uint4*)&actbuf[m*512 + ((kc ^ (m&7))<<3)] =
          *(const uint4*)(encB + (size_t)(m0+m)*64 + kc*8);
    }
  }
  __syncthreads();

  f32x4 h[4][4] = {};
  gemm_lds<2>(actbuf, wtin, 64, wn, fm, fk8, h);
  add_bias(b_in, wn, fm, h);

  for (int i=0;i<5;i++){
    gemm_lds<16>(albuf, wts + (size_t)i*262144, 512, wn, fm, fk8, h);
    add_bias(bz + i*512, wn, fm, h);
    __syncthreads();                       // prior actbuf readers done
    write_relu(actbuf, l, wn, h);          // actbuf = relu(h)
    __syncthreads();
    f32x4 acc[4][4] = {};
    gemm_lds<16>(actbuf, wts + (size_t)(5+i)*262144, 512, wn, fm, fk8, acc);
    add_bias(b0 + i*512, wn, fm, acc);
    __syncthreads();
    write_relu(actbuf, l, wn, acc);        // actbuf = relu(net)
    __syncthreads();
    gemm_lds<16>(actbuf, wts + (size_t)(10+i)*262144, 512, wn, fm, fk8, h);
    add_bias(b1 + i*512, wn, fm, h);
  }

  // sigma = exp(relu(h) . wout + bout)
  float s[4][4];
  #pragma unroll
  for (int mt=0;mt<4;mt++)
    #pragma unroll
    for (int r=0;r<4;r++){
      float a = 0.f;
      #pragma unroll
      for (int nt=0;nt<4;nt++)
        a += fmaxf(h[mt][nt][r], 0.f) * wout[wn + nt*16 + fm];
      s[mt][r] = a;
    }
  #pragma unroll
  for (int off=1; off<16; off<<=1)
    #pragma unroll
    for (int mt=0;mt<4;mt++)
      #pragma unroll
      for (int r=0;r<4;r++)
        s[mt][r] += __shfl_xor(s[mt][r], off, 64);
  __syncthreads();                 // actbuf dead; reuse as float red[8][64]
  float* red = (float*)actbuf;
  if (fm == 0){
    int rq = (l>>4)*4;
    #pragma unroll
    for (int mt=0;mt<4;mt++)
      #pragma unroll
      for (int r=0;r<4;r++)
        red[w*64 + mt*16 + rq + r] = s[mt][r];
  }
  __syncthreads();
  if (t < 64){
    float a = bout[0];
    #pragma unroll
    for (int wv=0; wv<8; wv++) a += red[wv*64 + t];
    out[m0 + t] = expf(a);
  }
}

extern "C" void kernel_launch(void* const* d_in, const int* in_sizes, int n_in,
                              void* d_out, int out_size, void* d_ws, size_t ws_size,
                              hipStream_t stream) {
  const float* world = (const float*)d_in[0];
  const float* c2w   = (const float*)d_in[1];
  const float* kmat  = (const float*)d_in[2];
  const float* feat  = (const float*)d_in[3];
  const float* w_in  = (const float*)d_in[4];
  const float* b_in  = (const float*)d_in[5];
  const float* w_z   = (const float*)d_in[6];
  const float* b_z   = (const float*)d_in[7];
  const float* w_f0  = (const float*)d_in[8];
  const float* b_f0  = (const float*)d_in[9];
  const float* w_f1  = (const float*)d_in[10];
  const float* b_f1  = (const float*)d_in[11];
  const float* w_out = (const float*)d_in[12];
  const float* b_out = (const float*)d_in[13];
  float* out = (float*)d_out;
  char* ws = (char*)d_ws;

  size_t off = 0;
  u16* wts   = (u16*)(ws + off); off += (size_t)15*262144*2;       // 15x (512n x 512k) bf16
  u16* wtin  = (u16*)(ws + off); off += (size_t)512*64*2;          // (512n x 64k) bf16
  u16* featT = (u16*)(ws + off); off += (size_t)2*128*128*512*2;   // transposed features
  u16* alignedB = (u16*)(ws + off); off += (size_t)P_TOTAL*512*2;  // sampled features bf16
  u16* encB  = (u16*)(ws + off); off += (size_t)P_TOTAL*64*2;      // positional enc bf16

  k_wtrans15<<<dim3(16,16,15), 256, 0, stream>>>(w_z, w_f0, w_f1, wts);
  k_wtrans_in<<<dim3(2,16,1), 256, 0, stream>>>(w_in, wtin);
  k_featT<<<dim3(64,128,2), 128, 0, stream>>>(feat, featT);
  k_points<<<dim3(P_TOTAL/4), 256, 0, stream>>>(world, c2w, kmat, featT, alignedB, encB);
  k_net<<<dim3(P_TOTAL/64), 512, 0, stream>>>(alignedB, encB, wtin, b_in, wts,
      b_z, b_f0, b_f1, w_out, b_out, out);
}

// Round 5
// 1686.986 us; speedup vs baseline: 1.6588x; 1.0266x over previous
//
#include <hip/hip_runtime.h>

typedef __bf16 bf16_t;
typedef bf16_t bf16x8 __attribute__((ext_vector_type(8)));
typedef float f32x4 __attribute__((ext_vector_type(4)));
typedef unsigned short u16;

#define P_TOTAL 98304
#define PTS_PER_BATCH 49152

__device__ __forceinline__ u16 f2bs(float f){ bf16_t b=(bf16_t)f; return __builtin_bit_cast(u16,b); }

// ---------- weight transpose: (K,N) fp32 -> (N,K) bf16 ----------
__global__ void k_wtrans15(const float* __restrict__ lz, const float* __restrict__ f0,
                           const float* __restrict__ f1, u16* __restrict__ dst){
  __shared__ float tile[32][33];
  int z = blockIdx.z;
  const float* src = (z<5) ? (lz + (size_t)z*262144)
                   : (z<10 ? (f0 + (size_t)(z-5)*262144)
                           : (f1 + (size_t)(z-10)*262144));
  u16* d = dst + (size_t)z*262144;
  int k0 = blockIdx.x*32, n0 = blockIdx.y*32;
  int t = threadIdx.x, a = t&31, r = t>>5;
  #pragma unroll
  for (int p=0;p<4;p++) tile[r+p*8][a] = src[(size_t)(k0+r+p*8)*512 + n0+a];
  __syncthreads();
  #pragma unroll
  for (int p=0;p<4;p++) d[(size_t)(n0+r+p*8)*512 + k0+a] = f2bs(tile[a][r+p*8]);
}

__global__ void k_wtrans_in(const float* __restrict__ w, u16* __restrict__ dst){
  __shared__ float tile[32][33];
  int k0 = blockIdx.x*32, n0 = blockIdx.y*32;
  int t = threadIdx.x, a = t&31, r = t>>5;
  #pragma unroll
  for (int p=0;p<4;p++){
    int k = k0+r+p*8;
    tile[r+p*8][a] = (k < 63) ? w[(size_t)k*512 + n0+a] : 0.f;
  }
  __syncthreads();
  #pragma unroll
  for (int p=0;p<4;p++) dst[(size_t)(n0+r+p*8)*64 + k0+a] = f2bs(tile[a][r+p*8]);
}

// ---------- feature transpose: (B,512,128,128) f32 -> (B,128,128,512) bf16 ----------
__global__ void k_featT(const float* __restrict__ feat, u16* __restrict__ featT){
  int x = threadIdx.x;
  int c8 = blockIdx.x*8;
  int y = blockIdx.y, b = blockIdx.z;
  float v[8];
  #pragma unroll
  for (int j=0;j<8;j++)
    v[j] = feat[(((size_t)(b*512 + c8 + j))*128 + y)*128 + x];
  bf16x8 o;
  #pragma unroll
  for (int j=0;j<8;j++) o[j] = (bf16_t)v[j];
  *(bf16x8*)(featT + (((size_t)(b*128 + y))*128 + x)*512 + c8) = o;
}

// ---------- per-point: geometry + bilinear + positional encoding ----------
__global__ void k_points(const float* __restrict__ world, const float* __restrict__ c2w,
                         const float* __restrict__ kmat, const u16* __restrict__ featT,
                         u16* __restrict__ alignedB, u16* __restrict__ encB){
  int wid = threadIdx.x >> 6, lane = threadIdx.x & 63;
  int gp = blockIdx.x*4 + wid;
  int b = gp / PTS_PER_BATCH;
  const float* wp = world + (size_t)gp*3;
  float px = wp[0], py = wp[1], pz = wp[2];
  const float* cw = c2w + b*16;
  float dx = px - cw[3], dy = py - cw[7], dz = pz - cw[11];
  float cx = cw[0]*dx + cw[4]*dy + cw[8]*dz;
  float cy = cw[1]*dx + cw[5]*dy + cw[9]*dz;
  float cz = cw[2]*dx + cw[6]*dy + cw[10]*dz;
  const float* km = kmat + b*9;
  float u0 = km[0]*cx + km[1]*cy + km[2]*cz;
  float v0 = km[3]*cx + km[4]*cy + km[5]*cz;
  float zz = km[6]*cx + km[7]*cy + km[8]*cz;
  if (fabsf(zz) < 1e-6f) zz = 1e-6f;
  float uu = u0/zz, vv = v0/zz;
  float xf = fminf(fmaxf(uu, 0.f), 127.f);
  float yf = fminf(fmaxf(vv, 0.f), 127.f);
  float x0f = floorf(xf), y0f = floorf(yf);
  int x0 = (int)x0f, y0 = (int)y0f;
  int x1 = min(x0+1,127), y1 = min(y0+1,127);
  float wx = xf - x0f, wy = yf - y0f;
  float w00 = (1.f-wx)*(1.f-wy), w01 = wx*(1.f-wy), w10 = (1.f-wx)*wy, w11 = wx*wy;
  size_t fb = (size_t)b*128*128*512;
  int c8 = lane*8;
  const bf16x8 t00 = *(const bf16x8*)(featT + fb + (size_t)(y0*128+x0)*512 + c8);
  const bf16x8 t01 = *(const bf16x8*)(featT + fb + (size_t)(y0*128+x1)*512 + c8);
  const bf16x8 t10 = *(const bf16x8*)(featT + fb + (size_t)(y1*128+x0)*512 + c8);
  const bf16x8 t11 = *(const bf16x8*)(featT + fb + (size_t)(y1*128+x1)*512 + c8);
  bf16x8 o;
  #pragma unroll
  for (int j=0;j<8;j++){
    float r = (float)t00[j]*w00 + (float)t01[j]*w01 + (float)t10[j]*w10 + (float)t11[j]*w11;
    o[j] = (bf16_t)r;
  }
  *(bf16x8*)(alignedB + (size_t)gp*512 + c8) = o;
  float cam[3] = {cx, cy, cz};
  float e;
  if (lane < 3) e = cam[lane];
  else if (lane < 33){
    int i = (lane-3)/10, f = (lane-3)%10;
    e = sinf(6.2831855f * cam[i] * (float)(1<<f));
  } else if (lane < 63){
    int i = (lane-33)/10, f = (lane-33)%10;
    e = cosf(6.2831855f * cam[i] * (float)(1<<f));
  } else e = 0.f;
  encB[(size_t)gp*64 + lane] = f2bs(e);
}

// ============ fused persistent MLP (M=64/block) ============
// 512 thr (8 waves, 2/SIMD, 256 VGPR-class budget). wave w owns n-strip
// [w*64,w*64+64); h fp32 resident (64 acc regs, C-layout). albuf: aligned tile
// (64KB, staged once); actbuf: activation tile (64KB). Weights (N,K) bf16
// streamed from global (L2-broadcast) with rolled 1-chunk register dbuf.
// NOTE: K-loop must stay ROLLED (unroll 2 max) — full unroll => spill (round 4).

template<int NK>
__device__ __forceinline__ void gemm_lds(const u16* sA, const u16* __restrict__ Bt, int ldb,
                                         int wn, int fm, int fk8, f32x4 (&acc)[4][4]){
  const u16* bp = Bt + (size_t)(wn + fm)*ldb + fk8*8;
  bf16x8 b[4];
  #pragma unroll
  for (int nt=0;nt<4;nt++)
    b[nt] = *(const bf16x8*)(bp + nt*16*ldb);
  #pragma unroll 2
  for (int kt=0; kt<NK-1; ++kt){
    bf16x8 bn[4];
    #pragma unroll
    for (int nt=0;nt<4;nt++)
      bn[nt] = *(const bf16x8*)(bp + nt*16*ldb + (kt+1)*32);
    bf16x8 a[4];
    #pragma unroll
    for (int mt=0;mt<4;mt++){
      int m = mt*16 + fm;
      int kc = kt*4 + fk8;
      a[mt] = *(const bf16x8*)&sA[m*512 + ((kc ^ (m&7))<<3)];
    }
    #pragma unroll
    for (int mt=0;mt<4;mt++)
      #pragma unroll
      for (int nt=0;nt<4;nt++)
        acc[mt][nt] = __builtin_amdgcn_mfma_f32_16x16x32_bf16(a[mt], b[nt], acc[mt][nt], 0,0,0);
    #pragma unroll
    for (int nt=0;nt<4;nt++) b[nt] = bn[nt];
  }
  { // epilogue chunk NK-1
    bf16x8 a[4];
    #pragma unroll
    for (int mt=0;mt<4;mt++){
      int m = mt*16 + fm;
      int kc = (NK-1)*4 + fk8;
      a[mt] = *(const bf16x8*)&sA[m*512 + ((kc ^ (m&7))<<3)];
    }
    #pragma unroll
    for (int mt=0;mt<4;mt++)
      #pragma unroll
      for (int nt=0;nt<4;nt++)
        acc[mt][nt] = __builtin_amdgcn_mfma_f32_16x16x32_bf16(a[mt], b[nt], acc[mt][nt], 0,0,0);
  }
}

__device__ __forceinline__ void add_bias(const float* __restrict__ bias, int wn, int fm,
                                         f32x4 (&acc)[4][4]){
  #pragma unroll
  for (int nt=0;nt<4;nt++){
    float bv = bias[wn + nt*16 + fm];
    #pragma unroll
    for (int mt=0;mt<4;mt++)
      #pragma unroll
      for (int r=0;r<4;r++) acc[mt][nt][r] += bv;
  }
}

__device__ __forceinline__ void write_relu(u16* dst, int l, int wn, f32x4 (&acc)[4][4]){
  const int fm = l&15, rq = (l>>4)*4;
  #pragma unroll
  for (int mt=0;mt<4;mt++)
    #pragma unroll
    for (int nt=0;nt<4;nt++){
      int k = wn + nt*16 + fm;
      #pragma unroll
      for (int r=0;r<4;r++){
        int m = mt*16 + rq + r;
        dst[m*512 + ((((k>>3) ^ (m&7))<<3) | (k&7))] = f2bs(fmaxf(acc[mt][nt][r], 0.f));
      }
    }
}

// stage 64x512 bf16 row-major global tile -> swizzled LDS
__device__ __forceinline__ void stage_tile(u16* dst, const u16* __restrict__ src, int t){
  int m = t>>3, g = t&7;
  #pragma unroll
  for (int j=0;j<8;j++){
    int kc = g*8 + j;
    *(uint4*)&dst[m*512 + ((kc ^ (m&7))<<3)] =
        *(const uint4*)(src + (size_t)m*512 + kc*8);
  }
}

__global__ __launch_bounds__(512, 2) void k_net(
    const u16* __restrict__ alignedB, const u16* __restrict__ encB,
    const u16* __restrict__ wtin, const float* __restrict__ b_in,
    const u16* __restrict__ wts, const float* __restrict__ bz,
    const float* __restrict__ b0, const float* __restrict__ b1,
    const float* __restrict__ wout, const float* __restrict__ bout,
    float* __restrict__ out)
{
  __shared__ u16 albuf[64*512];    // aligned features, persistent (64 KB)
  __shared__ u16 actbuf[64*512];   // activation tile (64 KB)
  const int t = threadIdx.x, w = t>>6, l = t&63;
  const int m0 = blockIdx.x*64;
  const int wn = w*64, fm = l&15, fk8 = l>>4;

  // stage aligned tile once
  stage_tile(albuf, alignedB + (size_t)m0*512, t);
  // stage enc[m0:m0+64][0:64] (first 256 threads)
  if (t < 256){
    int m = t>>2;
    #pragma unroll
    for (int j=0;j<2;j++){
      int kc = (t&3)*2 + j;
      *(uint4*)&actbuf[m*512 + ((kc ^ (m&7))<<3)] =
          *(const uint4*)(encB + (size_t)(m0+m)*64 + kc*8);
    }
  }
  __syncthreads();

  f32x4 h[4][4] = {};
  gemm_lds<2>(actbuf, wtin, 64, wn, fm, fk8, h);
  add_bias(b_in, wn, fm, h);

  for (int i=0;i<5;i++){
    gemm_lds<16>(albuf, wts + (size_t)i*262144, 512, wn, fm, fk8, h);
    add_bias(bz + i*512, wn, fm, h);
    __syncthreads();                       // prior actbuf readers done
    write_relu(actbuf, l, wn, h);          // actbuf = relu(h)
    __syncthreads();
    f32x4 acc[4][4] = {};
    gemm_lds<16>(actbuf, wts + (size_t)(5+i)*262144, 512, wn, fm, fk8, acc);
    add_bias(b0 + i*512, wn, fm, acc);
    __syncthreads();
    write_relu(actbuf, l, wn, acc);        // actbuf = relu(net)
    __syncthreads();
    gemm_lds<16>(actbuf, wts + (size_t)(10+i)*262144, 512, wn, fm, fk8, h);
    add_bias(b1 + i*512, wn, fm, h);
  }

  // sigma = exp(relu(h) . wout + bout)
  float s[4][4];
  #pragma unroll
  for (int mt=0;mt<4;mt++)
    #pragma unroll
    for (int r=0;r<4;r++){
      float a = 0.f;
      #pragma unroll
      for (int nt=0;nt<4;nt++)
        a += fmaxf(h[mt][nt][r], 0.f) * wout[wn + nt*16 + fm];
      s[mt][r] = a;
    }
  #pragma unroll
  for (int off=1; off<16; off<<=1)
    #pragma unroll
    for (int mt=0;mt<4;mt++)
      #pragma unroll
      for (int r=0;r<4;r++)
        s[mt][r] += __shfl_xor(s[mt][r], off, 64);
  __syncthreads();                 // actbuf dead; reuse as float red[8][64]
  float* red = (float*)actbuf;
  if (fm == 0){
    int rq = (l>>4)*4;
    #pragma unroll
    for (int mt=0;mt<4;mt++)
      #pragma unroll
      for (int r=0;r<4;r++)
        red[w*64 + mt*16 + rq + r] = s[mt][r];
  }
  __syncthreads();
  if (t < 64){
    float a = bout[0];
    #pragma unroll
    for (int wv=0; wv<8; wv++) a += red[wv*64 + t];
    out[m0 + t] = expf(a);
  }
}

extern "C" void kernel_launch(void* const* d_in, const int* in_sizes, int n_in,
                              void* d_out, int out_size, void* d_ws, size_t ws_size,
                              hipStream_t stream) {
  const float* world = (const float*)d_in[0];
  const float* c2w   = (const float*)d_in[1];
  const float* kmat  = (const float*)d_in[2];
  const float* feat  = (const float*)d_in[3];
  const float* w_in  = (const float*)d_in[4];
  const float* b_in  = (const float*)d_in[5];
  const float* w_z   = (const float*)d_in[6];
  const float* b_z   = (const float*)d_in[7];
  const float* w_f0  = (const float*)d_in[8];
  const float* b_f0  = (const float*)d_in[9];
  const float* w_f1  = (const float*)d_in[10];
  const float* b_f1  = (const float*)d_in[11];
  const float* w_out = (const float*)d_in[12];
  const float* b_out = (const float*)d_in[13];
  float* out = (float*)d_out;
  char* ws = (char*)d_ws;

  size_t off = 0;
  u16* wts   = (u16*)(ws + off); off += (size_t)15*262144*2;       // 15x (512n x 512k) bf16
  u16* wtin  = (u16*)(ws + off); off += (size_t)512*64*2;          // (512n x 64k) bf16
  u16* featT = (u16*)(ws + off); off += (size_t)2*128*128*512*2;   // transposed features
  u16* alignedB = (u16*)(ws + off); off += (size_t)P_TOTAL*512*2;  // sampled features bf16
  u16* encB  = (u16*)(ws + off); off += (size_t)P_TOTAL*64*2;      // positional enc bf16

  k_wtrans15<<<dim3(16,16,15), 256, 0, stream>>>(w_z, w_f0, w_f1, wts);
  k_wtrans_in<<<dim3(2,16,1), 256, 0, stream>>>(w_in, wtin);
  k_featT<<<dim3(64,128,2), 128, 0, stream>>>(feat, featT);
  k_points<<<dim3(P_TOTAL/4), 256, 0, stream>>>(world, c2w, kmat, featT, alignedB, encB);
  k_net<<<dim3(P_TOTAL/64), 512, 0, stream>>>(alignedB, encB, wtin, b_in, wts,
      b_z, b_f0, b_f1, w_out, b_out, out);
}